// Round 3
// baseline (729.619 us; speedup 1.0000x reference)
//
#include <hip/hip_runtime.h>

#define NN 50000
#define NE 600000
#define NG 512
#define HD 128
#define EPSV 1e-5f

__device__ inline void atomicAddF(float* p, float v) {
  __hip_atomic_fetch_add(p, v, __ATOMIC_RELAXED, __HIP_MEMORY_SCOPE_AGENT);
}

// ---- CSR build (with self-edge first in each node's list) ----
__global__ __launch_bounds__(256) void k_count(const int* __restrict__ dst, int* __restrict__ cnt) {
  int e = blockIdx.x * 256 + threadIdx.x;
  if (e < NE) atomicAdd(&cnt[dst[e]], 1);
}

__global__ __launch_bounds__(1024) void k_scan(const int* __restrict__ cnt, int* __restrict__ off,
                                               int* __restrict__ cursor, float* __restrict__ dinv,
                                               int* __restrict__ csr) {
  __shared__ int part[16];
  __shared__ int partscan[16];
  int t = threadIdx.x;
  int lane = t & 63, w = t >> 6;
  int carry = 0;
  for (int base = 0; base < NN; base += 1024) {
    int idx = base + t;
    int c = (idx < NN) ? cnt[idx] : 0;
    int v = (idx < NN) ? (c + 1) : 0;   // +1 slot for self-edge
    int val = v;
#pragma unroll
    for (int s = 1; s < 64; s <<= 1) {
      int u = __shfl_up(val, s);
      if (lane >= s) val += u;
    }
    if (lane == 63) part[w] = val;
    __syncthreads();
    if (t == 0) {
      int acc = 0;
#pragma unroll
      for (int i = 0; i < 16; i++) { acc += part[i]; partscan[i] = acc; }
    }
    __syncthreads();
    int waveoff = (w > 0) ? partscan[w - 1] : 0;
    int incl = val + waveoff + carry;
    if (idx < NN) {
      int o = incl - v;
      off[idx] = o;
      cursor[idx] = o + 1;   // edges go after the self slot
      csr[o] = idx;          // self-edge
      dinv[idx] = rsqrtf((float)c + 1.0f);
    }
    carry += partscan[15];
    __syncthreads();
  }
  if (t == 0) off[NN] = carry;
}

__global__ __launch_bounds__(256) void k_fill(const int* __restrict__ src, const int* __restrict__ dst,
                                              int* __restrict__ cursor, int* __restrict__ csr) {
  int e = blockIdx.x * 256 + threadIdx.x;
  if (e < NE) {
    int p = atomicAdd(&cursor[dst[e]], 1);
    csr[p] = src[e];
  }
}

// ---- fused embedding tables: T = emb @ W1[rows] ----
__global__ __launch_bounds__(128) void k_tabs(const float* __restrict__ emb0, const float* __restrict__ emb1,
                                              const float* __restrict__ emb2, const float* __restrict__ emb5,
                                              const float* __restrict__ W1, float* __restrict__ tabs,
                                              float* __restrict__ row0) {
  int r = blockIdx.x, f = threadIdx.x;
  if (r == 470) { row0[f] = W1[f]; return; }
  const float* e;
  int wbase;
  if (r < 96)      { e = emb0 + r * 32;        wbase = 1;  }
  else if (r < 192){ e = emb1 + (r - 96) * 32; wbase = 33; }
  else if (r < 288){ e = emb2 + (r - 192) * 32; wbase = 65; }
  else             { e = emb5 + (r - 288) * 32; wbase = 97; }
  float acc = 0.f;
#pragma unroll 8
  for (int k = 0; k < 32; k++) acc += e[k] * W1[(wbase + k) * HD + f];
  tabs[r * HD + f] = acc;
}

// ---- layer-1: embed + axpy + pre-scale by dinv ----
__global__ __launch_bounds__(256) void k_embed(const float* __restrict__ x, const float* __restrict__ tabs,
                                               const float* __restrict__ row0, const float* __restrict__ dinv,
                                               float* __restrict__ A) {
  int n = blockIdx.x * 2 + (threadIdx.x >> 7);
  int f = threadIdx.x & 127;
  if (n >= NN) return;
  float poss = x[n * 5 + 0];
  int i0 = (int)x[n * 5 + 1];
  int i1 = (int)x[n * 5 + 2];
  int i2 = (int)x[n * 5 + 3];
  int i5 = (int)x[n * 5 + 4];
  float hw = poss * row0[f] + tabs[i0 * HD + f] + tabs[(96 + i1) * HD + f] +
             tabs[(192 + i2) * HD + f] + tabs[(288 + i5) * HD + f];
  A[n * HD + f] = hw * dinv[n];
}

// ---- aggregation: streaming segmented sum, depth-2 pipelined gathers ----
// CSR list per node = [self, neighbors...]; B[n] = dinv[n]*sum(A[list]) + bias.
#define AGG_NPW 6
#define AGG_NPB (4 * AGG_NPW)
__global__ __launch_bounds__(256) void k_agg(const float* __restrict__ A, const int* __restrict__ off,
                                             const int* __restrict__ csr, const float* __restrict__ dinv,
                                             const float* __restrict__ bias, float* __restrict__ B,
                                             float* __restrict__ stats) {
  const int t = threadIdx.x, lane = t & 63, wave = t >> 6;
  const float2* __restrict__ A2 = (const float2*)A;
  float2* __restrict__ B2 = (float2*)B;
  const float2 bias2 = ((const float2*)bias)[lane];
  float2 st1 = make_float2(0.f, 0.f), st2 = make_float2(0.f, 0.f);

  const int n0 = blockIdx.x * AGG_NPB + wave * AGG_NPW;
  int sv = 0; float dvv = 0.f;
  {
    int q = n0 + lane;
    if (lane <= AGG_NPW) sv = off[q > NN ? NN : q];
    if (lane < AGG_NPW && q < NN) dvv = dinv[q];
  }
  const int s0 = __shfl(sv, 0);
  const int T = __shfl(sv, AGG_NPW) - s0;
  const long b0 = s0;

  // preload up to 192 edge indices into 3 regs
  int ia = 0, ib = 0, ic = 0;
  if (lane < T)        ia = csr[b0 + lane];
  if (lane + 64 < T)   ib = csr[b0 + 64 + lane];
  if (lane + 128 < T)  ic = csr[b0 + 128 + lane];

  float2 acc = make_float2(0.f, 0.f);
  int cur = 0;
  int rel_next = __shfl(sv, 1) - s0;
  float2 va[8], vb[8];

#define LOADB(arr, qq) { \
  _Pragma("unroll") \
  for (int k = 0; k < 8; k++) { \
    int qk = (qq) + k; \
    float2 vv = make_float2(0.f, 0.f); \
    if (qk < T) { \
      int idk; \
      if (qk < 192) { \
        int li = qk & 63; \
        int x0 = __shfl(ia, li), x1 = __shfl(ib, li), x2 = __shfl(ic, li); \
        idk = qk < 64 ? x0 : (qk < 128 ? x1 : x2); \
      } else { \
        idk = csr[b0 + qk]; \
      } \
      vv = A2[(size_t)idk * 64 + lane]; \
    } \
    arr[k] = vv; \
  } }

#define FLUSH() { \
  int nn = n0 + cur; \
  if (nn < NN) { \
    float dv = __shfl(dvv, cur); \
    float2 o; \
    o.x = fmaf(acc.x, dv, bias2.x); \
    o.y = fmaf(acc.y, dv, bias2.y); \
    B2[(size_t)nn * 64 + lane] = o; \
    st1.x += o.x; st1.y += o.y; \
    st2.x += o.x * o.x; st2.y += o.y * o.y; \
  } \
  cur++; acc.x = 0.f; acc.y = 0.f; }

#define PROC(arr, qq) { \
  _Pragma("unroll") \
  for (int k = 0; k < 8; k++) { \
    int qk = (qq) + k; \
    if (qk >= T) break; \
    while (qk >= rel_next) { FLUSH(); rel_next = __shfl(sv, cur + 1) - s0; } \
    acc.x += arr[k].x; acc.y += arr[k].y; \
  } }

  if (T > 0) {
    LOADB(va, 0);
    int q = 0;
    while (true) {
      if (q + 8 < T) LOADB(vb, q + 8);
      PROC(va, q);
      q += 8; if (q >= T) break;
      if (q + 8 < T) LOADB(va, q + 8);
      PROC(vb, q);
      q += 8; if (q >= T) break;
    }
  }
  while (cur < AGG_NPW) { FLUSH(); }

#undef LOADB
#undef FLUSH
#undef PROC

  // block-level BN-stat reduction
  __shared__ float2 red[256];
  red[t] = st1;
  __syncthreads();
  float2 t1;
  if (wave == 0) {
    t1.x = red[lane].x + red[lane + 64].x + red[lane + 128].x + red[lane + 192].x;
    t1.y = red[lane].y + red[lane + 64].y + red[lane + 128].y + red[lane + 192].y;
  }
  __syncthreads();
  red[t] = st2;
  __syncthreads();
  if (wave == 0) {
    float2 t2;
    t2.x = red[lane].x + red[lane + 64].x + red[lane + 128].x + red[lane + 192].x;
    t2.y = red[lane].y + red[lane + 64].y + red[lane + 128].y + red[lane + 192].y;
    atomicAddF(&stats[2 * lane + 0], t1.x);
    atomicAddF(&stats[2 * lane + 1], t1.y);
    atomicAddF(&stats[128 + 2 * lane + 0], t2.x);
    atomicAddF(&stats[128 + 2 * lane + 1], t2.y);
  }
}

// ---- BN finalize -> affine a,c ----
__global__ __launch_bounds__(128) void k_affine(const float* __restrict__ stats, const float* __restrict__ g,
                                                const float* __restrict__ be, float* __restrict__ af,
                                                float* __restrict__ cf) {
  int f = threadIdx.x;
  float mean = stats[f] * (1.f / NN);
  float var = stats[128 + f] * (1.f / NN) - mean * mean;
  var = fmaxf(var, 0.f);
  float inv = rsqrtf(var + EPSV);
  float a = g[f] * inv;
  af[f] = a;
  cf[f] = be[f] - mean * a;
}

// ---- GEMM: Aout[n,:] = dinv[n] * (relu(af*Bin[n,:]+cf) @ W) ----
// 128-node tile, K chunked by 32; LDS 34KB -> 4 blocks/CU.
#define GT_N 128
#define GT_KC 32
__global__ __launch_bounds__(256) void k_gemm(const float* __restrict__ Bin, const float* __restrict__ W,
                                              const float* __restrict__ af, const float* __restrict__ cf,
                                              const float* __restrict__ dinv, float* __restrict__ Aout) {
  __shared__ float hs[GT_KC * 132];
  __shared__ float ws[GT_KC * 132];
  const int t = threadIdx.x;
  const int base = blockIdx.x * GT_N;
  const int tx = t & 15, ty = t >> 4;
  float acc[8][8];
#pragma unroll
  for (int a = 0; a < 8; a++)
#pragma unroll
    for (int b = 0; b < 8; b++) acc[a][b] = 0.f;

  for (int k0 = 0; k0 < HD; k0 += GT_KC) {
    __syncthreads();
    {
      const float4* W4 = (const float4*)(W + k0 * HD);
#pragma unroll
      for (int i = t; i < 1024; i += 256) {
        int row = i >> 5, c4 = i & 31;
        float4 v = W4[i];
        *(float4*)&ws[row * 132 + c4 * 4] = v;
      }
    }
    {
#pragma unroll
      for (int i = t; i < 1024; i += 256) {
        int node = i >> 3, c4 = i & 7;
        int n = base + node;
        float4 v = make_float4(0.f, 0.f, 0.f, 0.f);
        if (n < NN) v = *(const float4*)&Bin[(size_t)n * HD + k0 + c4 * 4];
        int kk = c4 * 4;
        float r0 = fmaxf(fmaf(af[k0 + kk + 0], v.x, cf[k0 + kk + 0]), 0.f);
        float r1 = fmaxf(fmaf(af[k0 + kk + 1], v.y, cf[k0 + kk + 1]), 0.f);
        float r2 = fmaxf(fmaf(af[k0 + kk + 2], v.z, cf[k0 + kk + 2]), 0.f);
        float r3 = fmaxf(fmaf(af[k0 + kk + 3], v.w, cf[k0 + kk + 3]), 0.f);
        hs[(kk + 0) * 132 + node] = r0;
        hs[(kk + 1) * 132 + node] = r1;
        hs[(kk + 2) * 132 + node] = r2;
        hs[(kk + 3) * 132 + node] = r3;
      }
    }
    __syncthreads();
#pragma unroll
    for (int k = 0; k < GT_KC; k++) {
      float4 h0 = *(float4*)&hs[k * 132 + ty * 8];
      float4 h1 = *(float4*)&hs[k * 132 + ty * 8 + 4];
      float4 w0 = *(float4*)&ws[k * 132 + tx * 8];
      float4 w1 = *(float4*)&ws[k * 132 + tx * 8 + 4];
      float hh[8] = {h0.x, h0.y, h0.z, h0.w, h1.x, h1.y, h1.z, h1.w};
      float wv[8] = {w0.x, w0.y, w0.z, w0.w, w1.x, w1.y, w1.z, w1.w};
#pragma unroll
      for (int a = 0; a < 8; a++)
#pragma unroll
        for (int b = 0; b < 8; b++) acc[a][b] = fmaf(hh[a], wv[b], acc[a][b]);
    }
  }
#pragma unroll
  for (int a = 0; a < 8; a++) {
    int n = base + ty * 8 + a;
    if (n < NN) {
      float s = dinv[n];
      float4 o0 = make_float4(acc[a][0] * s, acc[a][1] * s, acc[a][2] * s, acc[a][3] * s);
      float4 o1 = make_float4(acc[a][4] * s, acc[a][5] * s, acc[a][6] * s, acc[a][7] * s);
      *(float4*)&Aout[(size_t)n * HD + tx * 8] = o0;
      *(float4*)&Aout[(size_t)n * HD + tx * 8 + 4] = o1;
    }
  }
}

// ---- graph boundaries via binary search on sorted batch ----
__global__ __launch_bounds__(128) void k_bsearch(const int* __restrict__ batch, int* __restrict__ gstart) {
  int g = blockIdx.x * 128 + threadIdx.x;
  if (g > NG) return;
  if (g == NG) { gstart[NG] = NN; return; }
  int lo = 0, hi = NN;
  while (lo < hi) {
    int mid = (lo + hi) >> 1;
    if (batch[mid] < g) lo = mid + 1;
    else hi = mid;
  }
  gstart[g] = lo;
}

// ---- pool + FC ----
__global__ __launch_bounds__(128) void k_pool(const float* __restrict__ B, const float* __restrict__ af,
                                              const float* __restrict__ cf, const int* __restrict__ gstart,
                                              const float* __restrict__ fcW, const float* __restrict__ fcb,
                                              float* __restrict__ out) {
  int g = blockIdx.x, f = threadIdx.x;
  int gs = gstart[g], ge = gstart[g + 1];
  float a = af[f], c = cf[f];
  float acc = 0.f;
  for (int n = gs; n < ge; n++) acc += fmaxf(a * B[(size_t)n * HD + f] + c, 0.f);
  float cntf = (float)(ge - gs);
  float pooled = acc / fmaxf(cntf, 1.f);
  __shared__ float lp[128];
  lp[f] = pooled;
  __syncthreads();
  if (f < 3) {
    float o = fcb[f];
    for (int k = 0; k < 128; k++) o += lp[k] * fcW[k * 3 + f];
    out[g * 3 + f] = o;
  }
}

extern "C" void kernel_launch(void* const* d_in, const int* in_sizes, int n_in,
                              void* d_out, int out_size, void* d_ws, size_t ws_size,
                              hipStream_t stream) {
  const float* x    = (const float*)d_in[0];
  const int* ei     = (const int*)d_in[1];
  const int* batch  = (const int*)d_in[2];
  const float* emb0 = (const float*)d_in[3];
  const float* emb1 = (const float*)d_in[4];
  const float* emb2 = (const float*)d_in[5];
  const float* emb5 = (const float*)d_in[6];
  const float* W1   = (const float*)d_in[7];
  const float* b1   = (const float*)d_in[8];
  const float* W2   = (const float*)d_in[9];
  const float* b2   = (const float*)d_in[10];
  const float* W3   = (const float*)d_in[11];
  const float* b3   = (const float*)d_in[12];
  const float* g1   = (const float*)d_in[13];
  const float* be1  = (const float*)d_in[14];
  const float* g2   = (const float*)d_in[15];
  const float* be2  = (const float*)d_in[16];
  const float* g3   = (const float*)d_in[17];
  const float* be3  = (const float*)d_in[18];
  const float* fcW  = (const float*)d_in[19];
  const float* fcb  = (const float*)d_in[20];
  float* out = (float*)d_out;

  const int* esrc = ei;
  const int* edst = ei + NE;

  char* p = (char*)d_ws;
  size_t o = 0;
  auto alloc = [&](size_t bytes) -> void* {
    o = (o + 255) & ~(size_t)255;
    void* r = p + o;
    o += bytes;
    return r;
  };
  int* cnt      = (int*)alloc(NN * 4);
  float* stats  = (float*)alloc(3 * 256 * 4);   // 3 layers x (sum,sumsq)
  size_t zbytes = o;                            // memset range covers cnt+stats
  int* off      = (int*)alloc((NN + 1) * 4);
  int* cursor   = (int*)alloc(NN * 4);
  int* csr      = (int*)alloc((size_t)(NE + NN) * 4);
  float* dinv   = (float*)alloc(NN * 4);
  float* tabs   = (float*)alloc(470 * HD * 4);
  float* row0   = (float*)alloc(HD * 4);
  float* affine = (float*)alloc(3 * 256 * 4);   // 3 layers x (a,c)
  int* gstart   = (int*)alloc((NG + 1) * 4);
  float* bufA   = (float*)alloc((size_t)NN * HD * 4);
  float* bufB   = (float*)alloc((size_t)NN * HD * 4);
  (void)ws_size; (void)n_in; (void)in_sizes; (void)out_size;

  hipMemsetAsync(d_ws, 0, zbytes, stream);

  k_count<<<(NE + 255) / 256, 256, 0, stream>>>(edst, cnt);
  k_scan<<<1, 1024, 0, stream>>>(cnt, off, cursor, dinv, csr);
  k_fill<<<(NE + 255) / 256, 256, 0, stream>>>(esrc, edst, cursor, csr);
  k_tabs<<<471, 128, 0, stream>>>(emb0, emb1, emb2, emb5, W1, tabs, row0);
  k_bsearch<<<5, 128, 0, stream>>>(batch, gstart);
  k_embed<<<NN / 2, 256, 0, stream>>>(x, tabs, row0, dinv, bufA);

  const int nagg = (NN + AGG_NPB - 1) / AGG_NPB;
  const int ngemm = (NN + GT_N - 1) / GT_N;

  // layer 1
  k_agg<<<nagg, 256, 0, stream>>>(bufA, off, csr, dinv, b1, bufB, stats + 0);
  k_affine<<<1, 128, 0, stream>>>(stats + 0, g1, be1, affine + 0, affine + 128);
  // layer 2
  k_gemm<<<ngemm, 256, 0, stream>>>(bufB, W2, affine + 0, affine + 128, dinv, bufA);
  k_agg<<<nagg, 256, 0, stream>>>(bufA, off, csr, dinv, b2, bufB, stats + 256);
  k_affine<<<1, 128, 0, stream>>>(stats + 256, g2, be2, affine + 256, affine + 384);
  // layer 3
  k_gemm<<<ngemm, 256, 0, stream>>>(bufB, W3, affine + 256, affine + 384, dinv, bufA);
  k_agg<<<nagg, 256, 0, stream>>>(bufA, off, csr, dinv, b3, bufB, stats + 512);
  k_affine<<<1, 128, 0, stream>>>(stats + 512, g3, be3, affine + 512, affine + 640);
  // pool + fc
  k_pool<<<NG, 128, 0, stream>>>(bufB, affine + 512, affine + 640, gstart, fcW, fcb, out);
}